// Round 1
// baseline (1334.978 us; speedup 1.0000x reference)
//
#include <hip/hip_runtime.h>

#define E_EDGES 160000
#define N_NODES 10000

// 24^(-0.5)
#define TEMP 0.20412414523193154f

__device__ __forceinline__ unsigned enc_f32(float x) {
    unsigned b = __float_as_uint(x);
    return b ^ ((b & 0x80000000u) ? 0xFFFFFFFFu : 0x80000000u);
}
__device__ __forceinline__ float dec_f32(unsigned k) {
    unsigned b = (k & 0x80000000u) ? (k ^ 0x80000000u) : ~k;
    return __uint_as_float(b);
}

// Kernel 1: per-edge MLP + equivariant conv + k/q scores + v; atomicMax for segment max.
__global__ __launch_bounds__(256, 2)
void edge_kernel(const int* __restrict__ src, const int* __restrict__ dst,
                 const float* __restrict__ basis, const float* __restrict__ efeat,
                 const float* __restrict__ f, const float* __restrict__ W1,
                 const float* __restrict__ b1, const float* __restrict__ W2,
                 const float* __restrict__ b2,
                 float* __restrict__ v_out, float* __restrict__ sc_out,
                 unsigned* __restrict__ smax)
{
    // per-thread private LDS: k rows (24 floats) + 4 score accumulators, stride 29 (odd -> conflict-free)
    __shared__ float lds[256 * 29];
    float* my = lds + threadIdx.x * 29;

    int e = blockIdx.x * blockDim.x + threadIdx.x;
    if (e >= E_EDGES) return;

    // ---- tmp2[(m*2+r)*3+d] = sum_d1 f[src][m][d1] * basis[e][d1][r*3+d] ----
    float fe[48];
    {
        const float4* fv = (const float4*)(f + (long)src[e] * 48);
        #pragma unroll
        for (int i = 0; i < 12; ++i) {
            float4 t = fv[i];
            fe[4*i+0] = t.x; fe[4*i+1] = t.y; fe[4*i+2] = t.z; fe[4*i+3] = t.w;
        }
    }
    float bas[18];
    {
        const float2* bv = (const float2*)(basis + (long)e * 18);
        #pragma unroll
        for (int i = 0; i < 9; ++i) { float2 t = bv[i]; bas[2*i] = t.x; bas[2*i+1] = t.y; }
    }
    float tmp2[96];
    #pragma unroll
    for (int m = 0; m < 16; ++m) {
        #pragma unroll
        for (int r = 0; r < 2; ++r) {
            #pragma unroll
            for (int d = 0; d < 3; ++d) {
                tmp2[(m*2+r)*3+d] =
                    fmaf(fe[m*3+0], bas[0*6 + r*3+d],
                    fmaf(fe[m*3+1], bas[1*6 + r*3+d],
                         fe[m*3+2] * bas[2*6 + r*3+d]));
            }
        }
    }

    // ---- h = relu(W1 @ x + b1) ----
    float x[32];
    {
        const float4* xv = (const float4*)(efeat + (long)e * 32);
        #pragma unroll
        for (int i = 0; i < 8; ++i) {
            float4 t = xv[i];
            x[4*i+0] = t.x; x[4*i+1] = t.y; x[4*i+2] = t.z; x[4*i+3] = t.w;
        }
    }
    float h[64];
    #pragma unroll
    for (int j = 0; j < 64; ++j) {
        float a = b1[j];
        #pragma unroll
        for (int i = 0; i < 32; ++i) a = fmaf(W1[j*32+i], x[i], a);
        h[j] = fmaxf(a, 0.0f);
    }

    // ---- conv rows: conv[c,d] = sum_m (b2[c*32+m] + W2[c*32+m,:] . h) * tmp2[m,d] ----
    #pragma unroll 1
    for (int c = 0; c < 24; ++c) {
        float a0 = 0.0f, a1 = 0.0f, a2 = 0.0f;
        #pragma unroll
        for (int m = 0; m < 32; ++m) {
            const float* __restrict__ w = W2 + (c*32 + m)*64;
            float rw = b2[c*32+m];
            #pragma unroll
            for (int j = 0; j < 64; ++j) rw = fmaf(w[j], h[j], rw);
            a0 = fmaf(rw, tmp2[m*3+0], a0);
            a1 = fmaf(rw, tmp2[m*3+1], a1);
            a2 = fmaf(rw, tmp2[m*3+2], a2);
        }
        if (c < 8) {                       // k row -> LDS
            my[c*3+0] = a0; my[c*3+1] = a1; my[c*3+2] = a2;
        } else if (c < 16) {               // q row -> score partial
            int hh = (c - 8) >> 1;
            float part = a0*my[(c-8)*3+0] + a1*my[(c-8)*3+1] + a2*my[(c-8)*3+2];
            if ((c & 1) == 0) my[24+hh] = part;
            else             my[24+hh] += part;
        } else {                           // v row -> global
            int o = e*24 + (c-16)*3;
            v_out[o+0] = a0; v_out[o+1] = a1; v_out[o+2] = a2;
        }
    }

    // ---- scores: scale, leaky-relu, store, atomic segment max ----
    float s0 = my[24] * TEMP, s1 = my[25] * TEMP, s2 = my[26] * TEMP, s3 = my[27] * TEMP;
    s0 = (s0 > 0.0f) ? s0 : 0.2f * s0;
    s1 = (s1 > 0.0f) ? s1 : 0.2f * s1;
    s2 = (s2 > 0.0f) ? s2 : 0.2f * s2;
    s3 = (s3 > 0.0f) ? s3 : 0.2f * s3;
    *(float4*)(sc_out + e*4) = make_float4(s0, s1, s2, s3);

    int dn = dst[e];
    atomicMax(&smax[dn*4+0], enc_f32(s0));
    atomicMax(&smax[dn*4+1], enc_f32(s1));
    atomicMax(&smax[dn*4+2], enc_f32(s2));
    atomicMax(&smax[dn*4+3], enc_f32(s3));
}

// Kernel 2: ex = exp(score - smax[dst]); accumulate denom and ex*v into out.
__global__ __launch_bounds__(256)
void scatter_kernel(const int* __restrict__ dst, const float* __restrict__ sc,
                    const float* __restrict__ v_in, const unsigned* __restrict__ smax,
                    float* __restrict__ denom, float* __restrict__ out)
{
    int e = blockIdx.x * blockDim.x + threadIdx.x;
    if (e >= E_EDGES) return;
    int dn = dst[e];

    float4 s = *(const float4*)(sc + e*4);
    float ex[4];
    ex[0] = __expf(s.x - dec_f32(smax[dn*4+0]));
    ex[1] = __expf(s.y - dec_f32(smax[dn*4+1]));
    ex[2] = __expf(s.z - dec_f32(smax[dn*4+2]));
    ex[3] = __expf(s.w - dec_f32(smax[dn*4+3]));

    atomicAdd(&denom[dn*4+0], ex[0]);
    atomicAdd(&denom[dn*4+1], ex[1]);
    atomicAdd(&denom[dn*4+2], ex[2]);
    atomicAdd(&denom[dn*4+3], ex[3]);

    const float4* vv = (const float4*)(v_in + e*24);
    float* ob = out + dn*24;
    #pragma unroll
    for (int i = 0; i < 6; ++i) {
        float4 t = vv[i];
        atomicAdd(&ob[4*i+0], t.x * ex[(4*i+0)/6]);
        atomicAdd(&ob[4*i+1], t.y * ex[(4*i+1)/6]);
        atomicAdd(&ob[4*i+2], t.z * ex[(4*i+2)/6]);
        atomicAdd(&ob[4*i+3], t.w * ex[(4*i+3)/6]);
    }
}

// Kernel 3: divide by denom (guard empty nodes -> 0, matching segment_sum semantics).
__global__ __launch_bounds__(256)
void finalize_kernel(const float* __restrict__ denom, float* __restrict__ out)
{
    int i = blockIdx.x * blockDim.x + threadIdx.x;
    if (i >= N_NODES * 24) return;
    int n = i / 24;
    int hh = (i % 24) / 6;
    float dn = denom[n*4 + hh];
    float o = out[i];
    out[i] = (dn > 0.0f) ? (o / dn) : 0.0f;
}

extern "C" void kernel_launch(void* const* d_in, const int* in_sizes, int n_in,
                              void* d_out, int out_size, void* d_ws, size_t ws_size,
                              hipStream_t stream)
{
    const int*   src   = (const int*)d_in[0];
    const int*   dst   = (const int*)d_in[1];
    const float* basis = (const float*)d_in[2];
    const float* ef    = (const float*)d_in[3];
    const float* f     = (const float*)d_in[4];
    const float* W1    = (const float*)d_in[5];
    const float* b1    = (const float*)d_in[6];
    const float* W2    = (const float*)d_in[7];
    const float* b2    = (const float*)d_in[8];
    float* out = (float*)d_out;

    float*    v_buf  = (float*)d_ws;                              // E*24
    float*    sc_buf = v_buf + (size_t)E_EDGES * 24;              // E*4
    unsigned* smax   = (unsigned*)(sc_buf + (size_t)E_EDGES * 4); // N*4
    float*    denom  = (float*)(smax + (size_t)N_NODES * 4);      // N*4

    hipMemsetAsync(smax, 0, (size_t)N_NODES * 4 * sizeof(unsigned), stream);
    hipMemsetAsync(denom, 0, (size_t)N_NODES * 4 * sizeof(float), stream);
    hipMemsetAsync(out, 0, (size_t)N_NODES * 24 * sizeof(float), stream);

    edge_kernel<<<E_EDGES / 256, 256, 0, stream>>>(src, dst, basis, ef, f, W1, b1, W2, b2,
                                                   v_buf, sc_buf, smax);
    scatter_kernel<<<E_EDGES / 256, 256, 0, stream>>>(dst, sc_buf, v_buf, smax, denom, out);
    int tot = N_NODES * 24;
    finalize_kernel<<<(tot + 255) / 256, 256, 0, stream>>>(denom, out);
}

// Round 2
// 708.830 us; speedup vs baseline: 1.8834x; 1.8834x over previous
//
#include <hip/hip_runtime.h>

#define E_EDGES 160000
#define N_NODES 10000

// 24^(-0.5)
#define TEMP 0.20412414523193154f

__device__ __forceinline__ unsigned enc_f32(float x) {
    unsigned b = __float_as_uint(x);
    return b ^ ((b & 0x80000000u) ? 0xFFFFFFFFu : 0x80000000u);
}
__device__ __forceinline__ float dec_f32(unsigned k) {
    unsigned b = (k & 0x80000000u) ? (k ^ 0x80000000u) : ~k;
    return __uint_as_float(b);
}
__device__ __forceinline__ unsigned short f2bf(float x) {
    unsigned b = __float_as_uint(x);
    b += 0x7FFFu + ((b >> 16) & 1u);   // RNE
    return (unsigned short)(b >> 16);
}

// per-thread LDS stride in ushorts: 3 planes x 32 m' = 96 halves + 2 pad = 98 (49 words, odd -> conflict-free)
#define T2_STRIDE 98

// Kernel 1: per-edge MLP + equivariant conv + per-head scores + v rows.
// tmp2 lives in private LDS (bf16); h[64] in VGPRs; no spills.
__global__ __launch_bounds__(256, 3)
void edge_kernel(const int* __restrict__ src, const int* __restrict__ dst,
                 const float* __restrict__ basis, const float* __restrict__ efeat,
                 const float* __restrict__ f, const float* __restrict__ W1,
                 const float* __restrict__ b1, const float* __restrict__ W2,
                 const float* __restrict__ b2,
                 float* __restrict__ v_out, float* __restrict__ sc_out,
                 unsigned* __restrict__ smax)
{
    __shared__ unsigned short t2[256 * T2_STRIDE];   // 50176 B
    unsigned short* mt = t2 + threadIdx.x * T2_STRIDE;

    int e = blockIdx.x * blockDim.x + threadIdx.x;

    // ---- tmp2[m'=2m+r][d] = sum_d1 f[src][m][d1] * basis[e][d1][r*3+d], store bf16 d-major ----
    {
        float bas[18];
        const float2* bv = (const float2*)(basis + (long)e * 18);
        #pragma unroll
        for (int i = 0; i < 9; ++i) { float2 t = bv[i]; bas[2*i] = t.x; bas[2*i+1] = t.y; }

        const float4* fv = (const float4*)(f + (long)src[e] * 48);
        float fe[48];
        #pragma unroll
        for (int i = 0; i < 12; ++i) {
            float4 t = fv[i];
            fe[4*i+0] = t.x; fe[4*i+1] = t.y; fe[4*i+2] = t.z; fe[4*i+3] = t.w;
        }
        #pragma unroll
        for (int m = 0; m < 16; ++m) {
            #pragma unroll
            for (int r = 0; r < 2; ++r) {
                #pragma unroll
                for (int d = 0; d < 3; ++d) {
                    float v = fmaf(fe[m*3+0], bas[0*6 + r*3+d],
                              fmaf(fe[m*3+1], bas[1*6 + r*3+d],
                                   fe[m*3+2] * bas[2*6 + r*3+d]));
                    mt[d*32 + (m*2+r)] = f2bf(v);
                }
            }
        }
    }

    // ---- h = relu(W1 @ x + b1) ----
    float h[64];
    {
        float x[32];
        const float4* xv = (const float4*)(efeat + (long)e * 32);
        #pragma unroll
        for (int i = 0; i < 8; ++i) {
            float4 t = xv[i];
            x[4*i+0] = t.x; x[4*i+1] = t.y; x[4*i+2] = t.z; x[4*i+3] = t.w;
        }
        #pragma unroll
        for (int j = 0; j < 64; ++j) {
            float a = b1[j];
            #pragma unroll
            for (int i = 0; i < 32; ++i) a = fmaf(W1[j*32+i], x[i], a);
            h[j] = fmaxf(a, 0.0f);
        }
    }

    int dn = dst[e];

    // ---- heads: for head ii, k rows {2ii,2ii+1}, q rows {8+2ii,9+2ii}; score in regs ----
    #pragma unroll 1
    for (int ii = 0; ii < 4; ++ii) {
        const int ck0 = 2*ii, ck1 = 2*ii + 1, cq0 = 8 + 2*ii, cq1 = 9 + 2*ii;
        float k00=0.f,k01=0.f,k02=0.f, k10=0.f,k11=0.f,k12=0.f;
        float q00=0.f,q01=0.f,q02=0.f, q10=0.f,q11=0.f,q12=0.f;
        #pragma unroll 2
        for (int m = 0; m < 32; ++m) {
            float r0 = b2[ck0*32+m], r1 = b2[ck1*32+m];
            float r2 = b2[cq0*32+m], r3 = b2[cq1*32+m];
            const float* __restrict__ w0 = W2 + (ck0*32+m)*64;
            const float* __restrict__ w1 = W2 + (ck1*32+m)*64;
            const float* __restrict__ w2 = W2 + (cq0*32+m)*64;
            const float* __restrict__ w3 = W2 + (cq1*32+m)*64;
            #pragma unroll
            for (int j = 0; j < 64; ++j) {
                r0 = fmaf(w0[j], h[j], r0);
                r1 = fmaf(w1[j], h[j], r1);
                r2 = fmaf(w2[j], h[j], r2);
                r3 = fmaf(w3[j], h[j], r3);
            }
            float t0 = __uint_as_float((unsigned)mt[0*32+m] << 16);
            float t1 = __uint_as_float((unsigned)mt[1*32+m] << 16);
            float t2v = __uint_as_float((unsigned)mt[2*32+m] << 16);
            k00 = fmaf(r0, t0, k00); k01 = fmaf(r0, t1, k01); k02 = fmaf(r0, t2v, k02);
            k10 = fmaf(r1, t0, k10); k11 = fmaf(r1, t1, k11); k12 = fmaf(r1, t2v, k12);
            q00 = fmaf(r2, t0, q00); q01 = fmaf(r2, t1, q01); q02 = fmaf(r2, t2v, q02);
            q10 = fmaf(r3, t0, q10); q11 = fmaf(r3, t1, q11); q12 = fmaf(r3, t2v, q12);
        }
        float s = k00*q00 + k01*q01 + k02*q02 + k10*q10 + k11*q11 + k12*q12;
        s *= TEMP;
        s = (s > 0.0f) ? s : 0.2f * s;
        sc_out[e*4 + ii] = s;
        atomicMax(&smax[dn*4 + ii], enc_f32(s));
    }

    // ---- v rows: c in [16,24) ----
    #pragma unroll 1
    for (int c = 16; c < 24; ++c) {
        float a0 = 0.f, a1 = 0.f, a2 = 0.f;
        #pragma unroll 2
        for (int m = 0; m < 32; ++m) {
            float rw = b2[c*32+m];
            const float* __restrict__ w = W2 + (c*32+m)*64;
            #pragma unroll
            for (int j = 0; j < 64; ++j) rw = fmaf(w[j], h[j], rw);
            float t0 = __uint_as_float((unsigned)mt[0*32+m] << 16);
            float t1 = __uint_as_float((unsigned)mt[1*32+m] << 16);
            float t2v = __uint_as_float((unsigned)mt[2*32+m] << 16);
            a0 = fmaf(rw, t0, a0);
            a1 = fmaf(rw, t1, a1);
            a2 = fmaf(rw, t2v, a2);
        }
        int o = e*24 + (c-16)*3;
        v_out[o+0] = a0; v_out[o+1] = a1; v_out[o+2] = a2;
    }
}

// Kernel 2: ex = exp(score - smax[dst]) (in-place over sc), accumulate denom.
__global__ __launch_bounds__(256)
void exp_kernel(const int* __restrict__ dst, float* __restrict__ sc,
                const unsigned* __restrict__ smax, float* __restrict__ denom)
{
    int e = blockIdx.x * blockDim.x + threadIdx.x;
    int dn = dst[e];
    float4 s = *(const float4*)(sc + e*4);
    float e0 = __expf(s.x - dec_f32(smax[dn*4+0]));
    float e1 = __expf(s.y - dec_f32(smax[dn*4+1]));
    float e2 = __expf(s.z - dec_f32(smax[dn*4+2]));
    float e3 = __expf(s.w - dec_f32(smax[dn*4+3]));
    *(float4*)(sc + e*4) = make_float4(e0, e1, e2, e3);
    atomicAdd(&denom[dn*4+0], e0);
    atomicAdd(&denom[dn*4+1], e1);
    atomicAdd(&denom[dn*4+2], e2);
    atomicAdd(&denom[dn*4+3], e3);
}

// Kernel 3: one thread per (edge, component) — 3.84M threads for atomic latency hiding.
__global__ __launch_bounds__(256)
void scatter_kernel(const int* __restrict__ dst, const float* __restrict__ ex,
                    const float* __restrict__ v_in, float* __restrict__ out)
{
    int t = blockIdx.x * blockDim.x + threadIdx.x;  // t < E*24
    int e = t / 24;
    int j = t - e * 24;
    float w = ex[e*4 + j/6];
    atomicAdd(&out[dst[e]*24 + j], v_in[t] * w);
}

// Kernel 4: divide by denom (empty nodes -> 0).
__global__ __launch_bounds__(256)
void finalize_kernel(const float* __restrict__ denom, float* __restrict__ out)
{
    int i = blockIdx.x * blockDim.x + threadIdx.x;
    if (i >= N_NODES * 24) return;
    int n = i / 24;
    int hh = (i % 24) / 6;
    float dn = denom[n*4 + hh];
    float o = out[i];
    out[i] = (dn > 0.0f) ? (o / dn) : 0.0f;
}

extern "C" void kernel_launch(void* const* d_in, const int* in_sizes, int n_in,
                              void* d_out, int out_size, void* d_ws, size_t ws_size,
                              hipStream_t stream)
{
    const int*   src   = (const int*)d_in[0];
    const int*   dst   = (const int*)d_in[1];
    const float* basis = (const float*)d_in[2];
    const float* ef    = (const float*)d_in[3];
    const float* f     = (const float*)d_in[4];
    const float* W1    = (const float*)d_in[5];
    const float* b1    = (const float*)d_in[6];
    const float* W2    = (const float*)d_in[7];
    const float* b2    = (const float*)d_in[8];
    float* out = (float*)d_out;

    float*    v_buf  = (float*)d_ws;                              // E*24
    float*    sc_buf = v_buf + (size_t)E_EDGES * 24;              // E*4 (scores, then ex in-place)
    unsigned* smax   = (unsigned*)(sc_buf + (size_t)E_EDGES * 4); // N*4
    float*    denom  = (float*)(smax + (size_t)N_NODES * 4);      // N*4

    hipMemsetAsync(smax, 0, (size_t)N_NODES * 4 * sizeof(unsigned), stream);
    hipMemsetAsync(denom, 0, (size_t)N_NODES * 4 * sizeof(float), stream);
    hipMemsetAsync(out, 0, (size_t)N_NODES * 24 * sizeof(float), stream);

    edge_kernel<<<E_EDGES / 256, 256, 0, stream>>>(src, dst, basis, ef, f, W1, b1, W2, b2,
                                                   v_buf, sc_buf, smax);
    exp_kernel<<<E_EDGES / 256, 256, 0, stream>>>(dst, sc_buf, smax, denom);
    scatter_kernel<<<(E_EDGES * 24) / 256, 256, 0, stream>>>(dst, sc_buf, v_buf, out);
    int tot = N_NODES * 24;
    finalize_kernel<<<(tot + 255) / 256, 256, 0, stream>>>(denom, out);
}

// Round 4
// 579.982 us; speedup vs baseline: 2.3018x; 1.2222x over previous
//
#include <hip/hip_runtime.h>

#define E_EDGES 160000
#define N_NODES 10000

// 24^(-0.5)
#define TEMP 0.20412414523193154f

typedef __fp16 half2_t __attribute__((ext_vector_type(2)));

__device__ __forceinline__ unsigned enc_f32(float x) {
    unsigned b = __float_as_uint(x);
    return b ^ ((b & 0x80000000u) ? 0xFFFFFFFFu : 0x80000000u);
}
__device__ __forceinline__ float dec_f32(unsigned k) {
    unsigned b = (k & 0x80000000u) ? (k ^ 0x80000000u) : ~k;
    return __uint_as_float(b);
}

__device__ __forceinline__ half2_t u2h(unsigned u) {
    union { unsigned u; half2_t h; } c; c.u = u; return c.h;
}

__device__ __forceinline__ float fdot2(half2_t a, half2_t b, float c) {
#if __has_builtin(__builtin_amdgcn_fdot2)
    return __builtin_amdgcn_fdot2(a, b, c, false);
#else
    return fmaf((float)a.x, (float)b.x, fmaf((float)a.y, (float)b.y, c));
#endif
}

__device__ __forceinline__ half2_t pk(float a, float b) {
    return __builtin_amdgcn_cvt_pkrtz(a, b);
}

// Kernel 0: W2 fp32 -> f16 pairs, row-major [768][64] -> [768][32] half2.
__global__ __launch_bounds__(256)
void w2cvt_kernel(const float* __restrict__ W2, unsigned* __restrict__ w2h)
{
    int t = blockIdx.x * blockDim.x + threadIdx.x;   // t < 24576
    float a = W2[2*t], b = W2[2*t+1];
    union { half2_t h; unsigned u; } c;
    c.h.x = (__fp16)a;  c.h.y = (__fp16)b;
    w2h[t] = c.u;
}

// Kernel 1: per-edge MLP + equivariant conv + per-head scores + v rows.
// All state in VGPRs (packed f16): hpk[32], t2pk[48]. No LDS, no dynamic-index arrays.
__global__ __launch_bounds__(256, 2)
void edge_kernel(const int* __restrict__ src, const int* __restrict__ dst,
                 const float* __restrict__ basis, const float* __restrict__ efeat,
                 const float* __restrict__ f, const float* __restrict__ W1,
                 const float* __restrict__ b1, const uint4* __restrict__ w2h,
                 const float* __restrict__ b2,
                 float* __restrict__ v_out, float* __restrict__ sc_out,
                 unsigned* __restrict__ smax)
{
    int e = blockIdx.x * blockDim.x + threadIdx.x;

    // ---- tmp2[m'=2m+r][d] packed over m'-pairs (same m, r=0/1), f16 ----
    half2_t t2pk[3][16];
    {
        float bas[18];
        const float2* bv = (const float2*)(basis + (size_t)e * 18);
        #pragma unroll
        for (int i = 0; i < 9; ++i) { float2 t = bv[i]; bas[2*i] = t.x; bas[2*i+1] = t.y; }

        float fe[48];
        const float4* fv = (const float4*)(f + (size_t)src[e] * 48);
        #pragma unroll
        for (int i = 0; i < 12; ++i) {
            float4 t = fv[i];
            fe[4*i+0] = t.x; fe[4*i+1] = t.y; fe[4*i+2] = t.z; fe[4*i+3] = t.w;
        }
        #pragma unroll
        for (int m = 0; m < 16; ++m) {
            #pragma unroll
            for (int d = 0; d < 3; ++d) {
                float v0 = fmaf(fe[m*3+0], bas[0*6 + d],
                           fmaf(fe[m*3+1], bas[1*6 + d],
                                fe[m*3+2] * bas[2*6 + d]));
                float v1 = fmaf(fe[m*3+0], bas[0*6 + 3 + d],
                           fmaf(fe[m*3+1], bas[1*6 + 3 + d],
                                fe[m*3+2] * bas[2*6 + 3 + d]));
                t2pk[d][m] = pk(v0, v1);
            }
        }
    }

    // ---- h = relu(W1 @ x + b1), packed to f16 pairs as we go ----
    half2_t hpk[32];
    {
        float x[32];
        const float4* xv = (const float4*)(efeat + (size_t)e * 32);
        #pragma unroll
        for (int i = 0; i < 8; ++i) {
            float4 t = xv[i];
            x[4*i+0] = t.x; x[4*i+1] = t.y; x[4*i+2] = t.z; x[4*i+3] = t.w;
        }
        #pragma unroll 4
        for (int jp = 0; jp < 32; ++jp) {
            float a0 = b1[2*jp], a1 = b1[2*jp+1];
            const float* __restrict__ w0 = W1 + (2*jp)*32;
            const float* __restrict__ w1 = W1 + (2*jp+1)*32;
            #pragma unroll
            for (int i = 0; i < 32; ++i) {
                a0 = fmaf(w0[i], x[i], a0);
                a1 = fmaf(w1[i], x[i], a1);
            }
            hpk[jp] = pk(fmaxf(a0, 0.0f), fmaxf(a1, 0.0f));
        }
    }

    int dn = dst[e];

    // ---- per head ii: rows {2ii,2ii+1}=k, {8+2ii,9+2ii}=q, {16+2ii,17+2ii}=v ----
    #pragma unroll 1
    for (int ii = 0; ii < 4; ++ii) {
        float acc[6][3];
        #pragma unroll
        for (int r = 0; r < 6; ++r) {
            acc[r][0] = 0.f; acc[r][1] = 0.f; acc[r][2] = 0.f;
        }
        #pragma unroll 2
        for (int mp = 0; mp < 16; ++mp) {
            const int coff[6] = {0, 1, 8, 9, 16, 17};
            #pragma unroll
            for (int rr = 0; rr < 6; ++rr) {
                const int crow = 2*ii + coff[rr];
                const uint4* __restrict__ wp0 = w2h + (size_t)(crow*32 + 2*mp) * 8;
                float2 bb = *(const float2*)(b2 + crow*32 + 2*mp);
                float rw0, rw1;
                {
                    float sa = 0.f, sb = 0.f, sc = 0.f, sd = 0.f;
                    #pragma unroll
                    for (int q = 0; q < 4; ++q) {
                        uint4 wA = wp0[q], wB = wp0[4+q];
                        sa = fdot2(u2h(wA.x), hpk[4*q+0], sa);
                        sa = fdot2(u2h(wA.y), hpk[4*q+1], sa);
                        sb = fdot2(u2h(wA.z), hpk[4*q+2], sb);
                        sb = fdot2(u2h(wA.w), hpk[4*q+3], sb);
                        sc = fdot2(u2h(wB.x), hpk[16+4*q+0], sc);
                        sc = fdot2(u2h(wB.y), hpk[16+4*q+1], sc);
                        sd = fdot2(u2h(wB.z), hpk[16+4*q+2], sd);
                        sd = fdot2(u2h(wB.w), hpk[16+4*q+3], sd);
                    }
                    rw0 = bb.x + (sa + sb) + (sc + sd);
                }
                {
                    const uint4* __restrict__ wp1 = wp0 + 8;
                    float sa = 0.f, sb = 0.f, sc = 0.f, sd = 0.f;
                    #pragma unroll
                    for (int q = 0; q < 4; ++q) {
                        uint4 wA = wp1[q], wB = wp1[4+q];
                        sa = fdot2(u2h(wA.x), hpk[4*q+0], sa);
                        sa = fdot2(u2h(wA.y), hpk[4*q+1], sa);
                        sb = fdot2(u2h(wA.z), hpk[4*q+2], sb);
                        sb = fdot2(u2h(wA.w), hpk[4*q+3], sb);
                        sc = fdot2(u2h(wB.x), hpk[16+4*q+0], sc);
                        sc = fdot2(u2h(wB.y), hpk[16+4*q+1], sc);
                        sd = fdot2(u2h(wB.z), hpk[16+4*q+2], sd);
                        sd = fdot2(u2h(wB.w), hpk[16+4*q+3], sd);
                    }
                    rw1 = bb.y + (sa + sb) + (sc + sd);
                }
                half2_t rwp = pk(rw0, rw1);
                acc[rr][0] = fdot2(rwp, t2pk[0][mp], acc[rr][0]);
                acc[rr][1] = fdot2(rwp, t2pk[1][mp], acc[rr][1]);
                acc[rr][2] = fdot2(rwp, t2pk[2][mp], acc[rr][2]);
            }
        }
        // score for head ii: k rows acc[0],acc[1]; q rows acc[2],acc[3]
        float s = acc[0][0]*acc[2][0] + acc[0][1]*acc[2][1] + acc[0][2]*acc[2][2]
                + acc[1][0]*acc[3][0] + acc[1][1]*acc[3][1] + acc[1][2]*acc[3][2];
        s *= TEMP;
        s = (s > 0.0f) ? s : 0.2f * s;
        sc_out[e*4 + ii] = s;
        atomicMax(&smax[dn*4 + ii], enc_f32(s));
        // v rows acc[4] (c=16+2ii), acc[5] (c=17+2ii) -> v_out[e][6*ii .. 6*ii+5]
        float2* vo = (float2*)(v_out + (size_t)e*24 + 6*ii);
        vo[0] = make_float2(acc[4][0], acc[4][1]);
        vo[1] = make_float2(acc[4][2], acc[5][0]);
        vo[2] = make_float2(acc[5][1], acc[5][2]);
    }
}

// Kernel 2: ex = exp(score - smax[dst]) (in-place over sc), accumulate denom.
__global__ __launch_bounds__(256)
void exp_kernel(const int* __restrict__ dst, float* __restrict__ sc,
                const unsigned* __restrict__ smax, float* __restrict__ denom)
{
    int e = blockIdx.x * blockDim.x + threadIdx.x;
    int dn = dst[e];
    float4 s = *(const float4*)(sc + e*4);
    float e0 = __expf(s.x - dec_f32(smax[dn*4+0]));
    float e1 = __expf(s.y - dec_f32(smax[dn*4+1]));
    float e2 = __expf(s.z - dec_f32(smax[dn*4+2]));
    float e3 = __expf(s.w - dec_f32(smax[dn*4+3]));
    *(float4*)(sc + e*4) = make_float4(e0, e1, e2, e3);
    atomicAdd(&denom[dn*4+0], e0);
    atomicAdd(&denom[dn*4+1], e1);
    atomicAdd(&denom[dn*4+2], e2);
    atomicAdd(&denom[dn*4+3], e3);
}

// Kernel 3: one thread per (edge, component).
__global__ __launch_bounds__(256)
void scatter_kernel(const int* __restrict__ dst, const float* __restrict__ ex,
                    const float* __restrict__ v_in, float* __restrict__ out)
{
    int t = blockIdx.x * blockDim.x + threadIdx.x;  // t < E*24
    int e = t / 24;
    int j = t - e * 24;
    float w = ex[e*4 + j/6];
    atomicAdd(&out[dst[e]*24 + j], v_in[t] * w);
}

// Kernel 4: divide by denom (empty nodes -> 0).
__global__ __launch_bounds__(256)
void finalize_kernel(const float* __restrict__ denom, float* __restrict__ out)
{
    int i = blockIdx.x * blockDim.x + threadIdx.x;
    if (i >= N_NODES * 24) return;
    int n = i / 24;
    int hh = (i % 24) / 6;
    float dn = denom[n*4 + hh];
    float o = out[i];
    out[i] = (dn > 0.0f) ? (o / dn) : 0.0f;
}

extern "C" void kernel_launch(void* const* d_in, const int* in_sizes, int n_in,
                              void* d_out, int out_size, void* d_ws, size_t ws_size,
                              hipStream_t stream)
{
    const int*   src   = (const int*)d_in[0];
    const int*   dst   = (const int*)d_in[1];
    const float* basis = (const float*)d_in[2];
    const float* ef    = (const float*)d_in[3];
    const float* f     = (const float*)d_in[4];
    const float* W1    = (const float*)d_in[5];
    const float* b1    = (const float*)d_in[6];
    const float* W2    = (const float*)d_in[7];
    const float* b2    = (const float*)d_in[8];
    float* out = (float*)d_out;

    float*    v_buf  = (float*)d_ws;                              // E*24
    float*    sc_buf = v_buf + (size_t)E_EDGES * 24;              // E*4 (scores, then ex in-place)
    unsigned* smax   = (unsigned*)(sc_buf + (size_t)E_EDGES * 4); // N*4
    float*    denom  = (float*)(smax + (size_t)N_NODES * 4);      // N*4
    unsigned* w2h    = (unsigned*)(denom + (size_t)N_NODES * 4);  // 24576 uints (96 KB)

    (void)hipMemsetAsync(smax, 0, (size_t)N_NODES * 4 * sizeof(unsigned), stream);
    (void)hipMemsetAsync(denom, 0, (size_t)N_NODES * 4 * sizeof(float), stream);
    (void)hipMemsetAsync(out, 0, (size_t)N_NODES * 24 * sizeof(float), stream);

    w2cvt_kernel<<<96, 256, 0, stream>>>(W2, w2h);
    edge_kernel<<<E_EDGES / 256, 256, 0, stream>>>(src, dst, basis, ef, f, W1, b1,
                                                   (const uint4*)w2h, b2,
                                                   v_buf, sc_buf, smax);
    exp_kernel<<<E_EDGES / 256, 256, 0, stream>>>(dst, sc_buf, smax, denom);
    scatter_kernel<<<(E_EDGES * 24) / 256, 256, 0, stream>>>(dst, sc_buf, v_buf, out);
    int tot = N_NODES * 24;
    finalize_kernel<<<(tot + 255) / 256, 256, 0, stream>>>(denom, out);
}

// Round 5
// 420.844 us; speedup vs baseline: 3.1721x; 1.3781x over previous
//
#include <hip/hip_runtime.h>

#define E_EDGES 160000
#define N_NODES 10000

// 24^(-0.5)
#define TEMP 0.20412414523193154f

typedef __fp16 half2_t __attribute__((ext_vector_type(2)));

__device__ __forceinline__ unsigned enc_f32(float x) {
    unsigned b = __float_as_uint(x);
    return b ^ ((b & 0x80000000u) ? 0xFFFFFFFFu : 0x80000000u);
}
__device__ __forceinline__ float dec_f32(unsigned k) {
    unsigned b = (k & 0x80000000u) ? (k ^ 0x80000000u) : ~k;
    return __uint_as_float(b);
}

__device__ __forceinline__ half2_t u2h(unsigned u) {
    union { unsigned u; half2_t h; } c; c.u = u; return c.h;
}
__device__ __forceinline__ unsigned h2u(half2_t h) {
    union { half2_t h; unsigned u; } c; c.h = h; return c.u;
}

__device__ __forceinline__ float fdot2(half2_t a, half2_t b, float c) {
#if __has_builtin(__builtin_amdgcn_fdot2)
    return __builtin_amdgcn_fdot2(a, b, c, false);
#else
    return fmaf((float)a.x, (float)b.x, fmaf((float)a.y, (float)b.y, c));
#endif
}

__device__ __forceinline__ half2_t pk(float a, float b) {
    return __builtin_amdgcn_cvt_pkrtz(a, b);
}

// Kernel 0: W2 fp32 -> f16 pairs, row-major [768][64] -> [768][32] half2.
__global__ __launch_bounds__(256)
void w2cvt_kernel(const float* __restrict__ W2, unsigned* __restrict__ w2h)
{
    int t = blockIdx.x * blockDim.x + threadIdx.x;   // t < 24576
    float a = W2[2*t], b = W2[2*t+1];
    union { half2_t h; unsigned u; } c;
    c.h.x = (__fp16)a;  c.h.y = (__fp16)b;
    w2h[t] = c.u;
}

// per-thread LDS stride in words: 48 used (3 d-planes x 16 m-pairs) + 1 pad = 49 (odd)
#define T2_STRIDE 49

// Kernel 1: per-edge MLP + equivariant conv + per-head scores + v rows.
// hpk[32] in VGPRs (ALL accesses constant-indexed); tmp2 packed-f16 in private LDS
// (dynamic mp index is fine there). No scratch.
__global__ __launch_bounds__(256, 3)
void edge_kernel(const int* __restrict__ src, const int* __restrict__ dst,
                 const float* __restrict__ basis, const float* __restrict__ efeat,
                 const float* __restrict__ f, const float* __restrict__ W1,
                 const float* __restrict__ b1, const uint4* __restrict__ w2h,
                 const float* __restrict__ b2,
                 float* __restrict__ v_out, float* __restrict__ sc_out,
                 unsigned* __restrict__ smax)
{
    __shared__ unsigned t2lds[256 * T2_STRIDE];   // 50176 B -> 3 blocks/CU
    unsigned* mt = t2lds + threadIdx.x * T2_STRIDE;

    int e = blockIdx.x * blockDim.x + threadIdx.x;

    // ---- tmp2[m'=2m+r][d], packed over r=0/1 pairs, f16, into private LDS ----
    {
        float bas[18];
        const float2* bv = (const float2*)(basis + (size_t)e * 18);
        #pragma unroll
        for (int i = 0; i < 9; ++i) { float2 t = bv[i]; bas[2*i] = t.x; bas[2*i+1] = t.y; }

        float fe[48];
        const float4* fv = (const float4*)(f + (size_t)src[e] * 48);
        #pragma unroll
        for (int i = 0; i < 12; ++i) {
            float4 t = fv[i];
            fe[4*i+0] = t.x; fe[4*i+1] = t.y; fe[4*i+2] = t.z; fe[4*i+3] = t.w;
        }
        #pragma unroll
        for (int m = 0; m < 16; ++m) {
            #pragma unroll
            for (int d = 0; d < 3; ++d) {
                float v0 = fmaf(fe[m*3+0], bas[0*6 + d],
                           fmaf(fe[m*3+1], bas[1*6 + d],
                                fe[m*3+2] * bas[2*6 + d]));
                float v1 = fmaf(fe[m*3+0], bas[0*6 + 3 + d],
                           fmaf(fe[m*3+1], bas[1*6 + 3 + d],
                                fe[m*3+2] * bas[2*6 + 3 + d]));
                mt[d*16 + m] = h2u(pk(v0, v1));
            }
        }
    }

    // ---- h = relu(W1 @ x + b1), packed to f16 pairs; FULLY unrolled (hpk in VGPRs) ----
    half2_t hpk[32];
    {
        float x[32];
        const float4* xv = (const float4*)(efeat + (size_t)e * 32);
        #pragma unroll
        for (int i = 0; i < 8; ++i) {
            float4 t = xv[i];
            x[4*i+0] = t.x; x[4*i+1] = t.y; x[4*i+2] = t.z; x[4*i+3] = t.w;
        }
        #pragma unroll
        for (int jp = 0; jp < 32; ++jp) {
            float a0 = b1[2*jp], a1 = b1[2*jp+1];
            const float* __restrict__ w0 = W1 + (2*jp)*32;
            const float* __restrict__ w1 = W1 + (2*jp+1)*32;
            #pragma unroll
            for (int i = 0; i < 32; ++i) {
                a0 = fmaf(w0[i], x[i], a0);
                a1 = fmaf(w1[i], x[i], a1);
            }
            hpk[jp] = pk(fmaxf(a0, 0.0f), fmaxf(a1, 0.0f));
        }
    }

    int dn = dst[e];

    // ---- per head ii: rows {2ii,2ii+1}=k, {8+2ii,9+2ii}=q, {16+2ii,17+2ii}=v ----
    #pragma unroll 1
    for (int ii = 0; ii < 4; ++ii) {
        float acc[6][3];
        #pragma unroll
        for (int r = 0; r < 6; ++r) { acc[r][0] = 0.f; acc[r][1] = 0.f; acc[r][2] = 0.f; }

        #pragma unroll 2
        for (int mp = 0; mp < 16; ++mp) {
            half2_t rwp[6];
            const int coff[6] = {0, 1, 8, 9, 16, 17};
            #pragma unroll
            for (int rr = 0; rr < 6; ++rr) {
                const int crow = 2*ii + coff[rr];
                const uint4* __restrict__ wp0 = w2h + (size_t)(crow*32 + 2*mp) * 8;
                float2 bb = *(const float2*)(b2 + crow*32 + 2*mp);
                float rw0, rw1;
                {
                    float sa = 0.f, sb = 0.f, sc = 0.f, sd = 0.f;
                    #pragma unroll
                    for (int q = 0; q < 4; ++q) {
                        uint4 wA = wp0[q], wB = wp0[4+q];
                        sa = fdot2(u2h(wA.x), hpk[4*q+0], sa);
                        sa = fdot2(u2h(wA.y), hpk[4*q+1], sa);
                        sb = fdot2(u2h(wA.z), hpk[4*q+2], sb);
                        sb = fdot2(u2h(wA.w), hpk[4*q+3], sb);
                        sc = fdot2(u2h(wB.x), hpk[16+4*q+0], sc);
                        sc = fdot2(u2h(wB.y), hpk[16+4*q+1], sc);
                        sd = fdot2(u2h(wB.z), hpk[16+4*q+2], sd);
                        sd = fdot2(u2h(wB.w), hpk[16+4*q+3], sd);
                    }
                    rw0 = bb.x + (sa + sb) + (sc + sd);
                }
                {
                    const uint4* __restrict__ wp1 = wp0 + 8;
                    float sa = 0.f, sb = 0.f, sc = 0.f, sd = 0.f;
                    #pragma unroll
                    for (int q = 0; q < 4; ++q) {
                        uint4 wA = wp1[q], wB = wp1[4+q];
                        sa = fdot2(u2h(wA.x), hpk[4*q+0], sa);
                        sa = fdot2(u2h(wA.y), hpk[4*q+1], sa);
                        sb = fdot2(u2h(wA.z), hpk[4*q+2], sb);
                        sb = fdot2(u2h(wA.w), hpk[4*q+3], sb);
                        sc = fdot2(u2h(wB.x), hpk[16+4*q+0], sc);
                        sc = fdot2(u2h(wB.y), hpk[16+4*q+1], sc);
                        sd = fdot2(u2h(wB.z), hpk[16+4*q+2], sd);
                        sd = fdot2(u2h(wB.w), hpk[16+4*q+3], sd);
                    }
                    rw1 = bb.y + (sa + sb) + (sc + sd);
                }
                rwp[rr] = pk(rw0, rw1);
            }
            // read tmp2 once per mp, reuse across the 6 rows
            half2_t t0 = u2h(mt[0*16 + mp]);
            half2_t t1 = u2h(mt[1*16 + mp]);
            half2_t t2 = u2h(mt[2*16 + mp]);
            #pragma unroll
            for (int rr = 0; rr < 6; ++rr) {
                acc[rr][0] = fdot2(rwp[rr], t0, acc[rr][0]);
                acc[rr][1] = fdot2(rwp[rr], t1, acc[rr][1]);
                acc[rr][2] = fdot2(rwp[rr], t2, acc[rr][2]);
            }
        }
        // score for head ii: k rows acc[0],acc[1]; q rows acc[2],acc[3]
        float s = acc[0][0]*acc[2][0] + acc[0][1]*acc[2][1] + acc[0][2]*acc[2][2]
                + acc[1][0]*acc[3][0] + acc[1][1]*acc[3][1] + acc[1][2]*acc[3][2];
        s *= TEMP;
        s = (s > 0.0f) ? s : 0.2f * s;
        sc_out[e*4 + ii] = s;
        atomicMax(&smax[dn*4 + ii], enc_f32(s));
        // v rows acc[4] (c=16+2ii), acc[5] (c=17+2ii)
        float2* vo = (float2*)(v_out + (size_t)e*24 + 6*ii);
        vo[0] = make_float2(acc[4][0], acc[4][1]);
        vo[1] = make_float2(acc[4][2], acc[5][0]);
        vo[2] = make_float2(acc[5][1], acc[5][2]);
    }
}

// Kernel 2: ex = exp(score - smax[dst]) (in-place over sc), accumulate denom.
__global__ __launch_bounds__(256)
void exp_kernel(const int* __restrict__ dst, float* __restrict__ sc,
                const unsigned* __restrict__ smax, float* __restrict__ denom)
{
    int e = blockIdx.x * blockDim.x + threadIdx.x;
    int dn = dst[e];
    float4 s = *(const float4*)(sc + e*4);
    float e0 = __expf(s.x - dec_f32(smax[dn*4+0]));
    float e1 = __expf(s.y - dec_f32(smax[dn*4+1]));
    float e2 = __expf(s.z - dec_f32(smax[dn*4+2]));
    float e3 = __expf(s.w - dec_f32(smax[dn*4+3]));
    *(float4*)(sc + e*4) = make_float4(e0, e1, e2, e3);
    atomicAdd(&denom[dn*4+0], e0);
    atomicAdd(&denom[dn*4+1], e1);
    atomicAdd(&denom[dn*4+2], e2);
    atomicAdd(&denom[dn*4+3], e3);
}

// Kernel 3: one thread per (edge, component).
__global__ __launch_bounds__(256)
void scatter_kernel(const int* __restrict__ dst, const float* __restrict__ ex,
                    const float* __restrict__ v_in, float* __restrict__ out)
{
    int t = blockIdx.x * blockDim.x + threadIdx.x;  // t < E*24
    int e = t / 24;
    int j = t - e * 24;
    float w = ex[e*4 + j/6];
    atomicAdd(&out[dst[e]*24 + j], v_in[t] * w);
}

// Kernel 4: divide by denom (empty nodes -> 0).
__global__ __launch_bounds__(256)
void finalize_kernel(const float* __restrict__ denom, float* __restrict__ out)
{
    int i = blockIdx.x * blockDim.x + threadIdx.x;
    if (i >= N_NODES * 24) return;
    int n = i / 24;
    int hh = (i % 24) / 6;
    float dn = denom[n*4 + hh];
    float o = out[i];
    out[i] = (dn > 0.0f) ? (o / dn) : 0.0f;
}

extern "C" void kernel_launch(void* const* d_in, const int* in_sizes, int n_in,
                              void* d_out, int out_size, void* d_ws, size_t ws_size,
                              hipStream_t stream)
{
    const int*   src   = (const int*)d_in[0];
    const int*   dst   = (const int*)d_in[1];
    const float* basis = (const float*)d_in[2];
    const float* ef    = (const float*)d_in[3];
    const float* f     = (const float*)d_in[4];
    const float* W1    = (const float*)d_in[5];
    const float* b1    = (const float*)d_in[6];
    const float* W2    = (const float*)d_in[7];
    const float* b2    = (const float*)d_in[8];
    float* out = (float*)d_out;

    float*    v_buf  = (float*)d_ws;                              // E*24
    float*    sc_buf = v_buf + (size_t)E_EDGES * 24;              // E*4 (scores, then ex in-place)
    unsigned* smax   = (unsigned*)(sc_buf + (size_t)E_EDGES * 4); // N*4
    float*    denom  = (float*)(smax + (size_t)N_NODES * 4);      // N*4
    unsigned* w2h    = (unsigned*)(denom + (size_t)N_NODES * 4);  // 24576 uints (96 KB)

    (void)hipMemsetAsync(smax, 0, (size_t)N_NODES * 4 * sizeof(unsigned), stream);
    (void)hipMemsetAsync(denom, 0, (size_t)N_NODES * 4 * sizeof(float), stream);
    (void)hipMemsetAsync(out, 0, (size_t)N_NODES * 24 * sizeof(float), stream);

    w2cvt_kernel<<<96, 256, 0, stream>>>(W2, w2h);
    edge_kernel<<<E_EDGES / 256, 256, 0, stream>>>(src, dst, basis, ef, f, W1, b1,
                                                   (const uint4*)w2h, b2,
                                                   v_buf, sc_buf, smax);
    exp_kernel<<<E_EDGES / 256, 256, 0, stream>>>(dst, sc_buf, smax, denom);
    scatter_kernel<<<(E_EDGES * 24) / 256, 256, 0, stream>>>(dst, sc_buf, v_buf, out);
    int tot = N_NODES * 24;
    finalize_kernel<<<(tot + 255) / 256, 256, 0, stream>>>(denom, out);
}